// Round 13
// baseline (620.632 us; speedup 1.0000x reference)
//
#include <hip/hip_runtime.h>

#define KK 12
#define LL 4096
#define DD 128
#define NN 16
#define RR 8
#define NC 256             // chunks (one per block)
#define LC 16              // chunk length = l-tile per block
#define XST 132            // x-tile / ybuf LDS stride (floats)
#define SDST 44            // x_dbl LDS row stride (floats)
#define XDBL_TILE (LC * SDST)   // 704 floats per (k,chunk) tile

__device__ __forceinline__ int pos_of(int k, int l) {
    int o = k >> 1;
    int le = (k & 1) ? (4095 - l) : l;
    int t1 = le >> 8, t2 = (le >> 4) & 15, t3 = le & 15;
    switch (o) {
        case 0:  return (t1 << 8) | (t2 << 4) | t3;
        case 1:  return (t1 << 8) | (t3 << 4) | t2;
        case 2:  return (t3 << 8) | (t2 << 4) | t1;
        case 3:  return (t2 << 8) | (t3 << 4) | t1;
        case 4:  return (t2 << 8) | (t1 << 4) | t3;
        default: return (t3 << 8) | (t1 << 4) | t2;
    }
}

__device__ __forceinline__ float delta_row_z(const float* sdbl, int l,
                                             float4 w0, float4 w1, float bz) {
    const float4* dr = (const float4*)(sdbl + l * SDST);
    float4 r0 = dr[0], r1 = dr[1];
    return bz + w0.x * r0.x + w0.y * r0.y + w0.z * r0.z + w0.w * r0.w
              + w1.x * r1.x + w1.y * r1.y + w1.z * r1.z + w1.w * r1.w;
}

// Structured requires A[n] = (n+1)*A0 AND A0 == -1 (true for this problem:
// A_logs = log(1..16)), so that exp(dt*A0) == exp(-dt) == (z>=0?E:1)/(1+E).
// A8 kept as two float4s (named components only — no arrays => no SROA risk,
// the R4/R5 scratch poisoning cannot recur via this path).
__device__ __forceinline__ bool load_A8(const float* __restrict__ A_logs,
                                        int k, int d, int n0,
                                        float4& A8a, float4& A8b, float& A0) {
    const float4* ap = (const float4*)(A_logs + ((size_t)(k * DD + d) * NN + n0));
    float4 a0 = ap[0], a1 = ap[1];
    A8a.x = -__expf(a0.x); A8a.y = -__expf(a0.y);
    A8a.z = -__expf(a0.z); A8a.w = -__expf(a0.w);
    A8b.x = -__expf(a1.x); A8b.y = -__expf(a1.y);
    A8b.z = -__expf(a1.z); A8b.w = -__expf(a1.w);
    A0 = -__expf(A_logs[(size_t)(k * DD + d) * NN]);
    float aA0 = fabsf(A0);
    bool s = (fabsf(A0 + 1.0f) <= 1e-5f);
    s = s && (fabsf(A8a.x - (float)(n0 + 1) * A0) <= 1e-4f * (float)(n0 + 1) * aA0);
    s = s && (fabsf(A8a.y - (float)(n0 + 2) * A0) <= 1e-4f * (float)(n0 + 2) * aA0);
    s = s && (fabsf(A8a.z - (float)(n0 + 3) * A0) <= 1e-4f * (float)(n0 + 3) * aA0);
    s = s && (fabsf(A8a.w - (float)(n0 + 4) * A0) <= 1e-4f * (float)(n0 + 4) * aA0);
    s = s && (fabsf(A8b.x - (float)(n0 + 5) * A0) <= 1e-4f * (float)(n0 + 5) * aA0);
    s = s && (fabsf(A8b.y - (float)(n0 + 6) * A0) <= 1e-4f * (float)(n0 + 6) * aA0);
    s = s && (fabsf(A8b.z - (float)(n0 + 7) * A0) <= 1e-4f * (float)(n0 + 7) * aA0);
    s = s && (fabsf(A8b.w - (float)(n0 + 8) * A0) <= 1e-4f * (float)(n0 + 8) * aA0);
    return s;
}

// ---------------------------------------------------------------------------
// One scan step — all state in named float4 components (spill-proof).
// ---------------------------------------------------------------------------
template<bool S>
__device__ __forceinline__ void scan_step(
    float* xs, const float* sdbl, int i, int d, int half, int n0,
    float4 A8a, float4 A8b, float dt, float q, float Dval,
    float4& hA, float4& hB, float& dsum)
{
    float u = xs[i * XST + d];
    dsum += dt;
    float tu = dt * u;
    float4 eA, eB;
    if constexpr (S) {
        float q2 = q * q, q4 = q2 * q2, q8 = q4 * q4;
        eA.x = half ? q8 * q : q;
        eA.y = eA.x * q;  eA.z = eA.y * q;  eA.w = eA.z * q;
        eB.x = eA.w * q;  eB.y = eB.x * q;  eB.z = eB.y * q;  eB.w = eB.z * q;
    } else {
        eA.x = __expf(dt * A8a.x); eA.y = __expf(dt * A8a.y);
        eA.z = __expf(dt * A8a.z); eA.w = __expf(dt * A8a.w);
        eB.x = __expf(dt * A8b.x); eB.y = __expf(dt * A8b.y);
        eB.z = __expf(dt * A8b.z); eB.w = __expf(dt * A8b.w);
    }
    const float4* bp = (const float4*)(&sdbl[i * SDST + 8 + n0]);
    float4 b0 = bp[0], b1 = bp[1];
    const float4* cp = (const float4*)(&sdbl[i * SDST + 24 + n0]);
    float4 c0 = cp[0], c1 = cp[1];
    hA.x = eA.x * hA.x + tu * b0.x;  hA.y = eA.y * hA.y + tu * b0.y;
    hA.z = eA.z * hA.z + tu * b0.z;  hA.w = eA.w * hA.w + tu * b0.w;
    hB.x = eB.x * hB.x + tu * b1.x;  hB.y = eB.y * hB.y + tu * b1.y;
    hB.z = eB.z * hB.z + tu * b1.z;  hB.w = eB.w * hB.w + tu * b1.w;
    float d0 = hA.x * c0.x + hA.y * c0.y;
    float d1 = hA.z * c0.z + hA.w * c0.w;
    float d2 = hB.x * c1.x + hB.y * c1.y;
    float d3 = hB.z * c1.z + hB.w * c1.w;
    float yp = (d0 + d1) + (d2 + d3);
    float yv = yp + __shfl_xor(yp, 1) + Dval * u;
    if (!half) xs[i * XST + d] = yv;
}

// ---------------------------------------------------------------------------
// K1 scan body. Pairwise delta via shfl_xor; #pragma unroll 1 pins the loop
// (R5 lesson: the 8-iteration trip count invites full unroll -> spills).
// ---------------------------------------------------------------------------
template<bool S>
__device__ __forceinline__ void scanA_body(
    float* xs, const float* sdbl, int k, int c,
    int d, int half, int n0, float4 A8a, float4 A8b,
    float4 w0, float4 w1, float bz, float Dval,
    float* __restrict__ S_g, float* __restrict__ dtsum)
{
    float4 hA = make_float4(0.f, 0.f, 0.f, 0.f);
    float4 hB = make_float4(0.f, 0.f, 0.f, 0.f);
    float dsum = 0.0f;

    #pragma unroll 1
    for (int i2 = 0; i2 < LC; i2 += 2) {
        float z = delta_row_z(sdbl, i2 + half, w0, w1, bz);
        float E = __expf(-fabsf(z));
        float opE = 1.0f + E;
        float dt = fmaxf(z, 0.0f) + __logf(opE);
        float q = 0.0f;
        if constexpr (S)
            q = (z >= 0.0f ? E : 1.0f) * __builtin_amdgcn_rcpf(opE);
        float dto = __shfl_xor(dt, 1);
        float qo  = S ? __shfl_xor(q, 1) : 0.0f;
        float dt0 = half ? dto : dt,  dt1 = half ? dt : dto;
        float q0  = half ? qo  : q,   q1  = half ? q  : qo;
        scan_step<S>(xs, sdbl, i2,     d, half, n0, A8a, A8b, dt0, q0, Dval, hA, hB, dsum);
        scan_step<S>(xs, sdbl, i2 + 1, d, half, n0, A8a, A8b, dt1, q1, Dval, hA, hB, dsum);
    }

    float4* sp = (float4*)(S_g + (((size_t)(k * NC + c) * DD + d) * NN + n0));
    sp[0] = hA;
    sp[1] = hB;
    if (!half) dtsum[(k * NC + c) * DD + d] = dsum;
}

// ---------------------------------------------------------------------------
// K1: proj GEMM + phase A local scan. Block = (k, 16-l chunk), 256 threads.
// LDS 11.3 KB, (256,4). Occupancy experiment: 3072 blocks = 12/CU of work
// (R4 measured 78% occupancy at this grid; goal is that WITHOUT the scratch).
// ---------------------------------------------------------------------------
__global__ __launch_bounds__(256, 4) void k1_proj_scanA(
    const float* __restrict__ x, const float* __restrict__ Wp,
    const float* __restrict__ Wdt, const float* __restrict__ bias,
    const float* __restrict__ A_logs, const float* __restrict__ Ds,
    float* __restrict__ S_g, float* __restrict__ dtsum,
    float* __restrict__ oy, float* __restrict__ xdbl)
{
    const int blk = blockIdx.x;
    const int k = blk >> 8;
    const int c = blk & 255;
    const int l0 = c * LC;
    const int t = threadIdx.x;

    __shared__ __align__(16) float xs[LC * XST];    // x-tile [l][d]; y overwrites
    __shared__ __align__(16) float sdbl[LC * SDST]; // x_dbl [l][ch]

    // ---- stage x tile: 2 passes x 8 rows x 32 lanes b128 (coalesced) ----
    {
        int lane32 = t & 31, rowi = t >> 5;
        #pragma unroll
        for (int p = 0; p < 2; p++) {
            int l = p * 8 + rowi;
            int pos = pos_of(k, l0 + l);
            float4 v = *(const float4*)(x + (size_t)pos * DD + lane32 * 4);
            *(float4*)(&xs[l * XST + lane32 * 4]) = v;
        }
    }
    __syncthreads();

    // ---- projection GEMM: 16 groups; groups 0-7 do 3 ch, 8-15 do 2 ch ----
    // (numerics verified: R4/R5 passed correctness with this exact block)
    {
        int l = t & 15, cg = t >> 4;
        bool n3 = (cg < 8);
        int ch0 = n3 ? cg * 3 : 24 + (cg - 8) * 2;
        float acc0 = 0.0f, acc1 = 0.0f, acc2 = 0.0f;
        const float* wk = Wp + (size_t)(k * 40 + ch0) * DD;
        for (int d4 = 0; d4 < DD; d4 += 4) {
            float4 xv = *(const float4*)(&xs[l * XST + d4]);
            const float* w0p = wk + d4;
            const float* w1p = wk + DD + d4;
            acc0 += xv.x * w0p[0] + xv.y * w0p[1] + xv.z * w0p[2] + xv.w * w0p[3];
            acc1 += xv.x * w1p[0] + xv.y * w1p[1] + xv.z * w1p[2] + xv.w * w1p[3];
            if (n3) {
                const float* w2p = wk + 2 * DD + d4;
                acc2 += xv.x * w2p[0] + xv.y * w2p[1] + xv.z * w2p[2] + xv.w * w2p[3];
            }
        }
        sdbl[l * SDST + ch0]     = acc0;
        sdbl[l * SDST + ch0 + 1] = acc1;
        if (n3) sdbl[l * SDST + ch0 + 2] = acc2;
    }
    __syncthreads();

    // ---- spill full x_dbl tile (704 floats) for K3 ----
    if (t < XDBL_TILE / 4) {
        ((float4*)(xdbl + (size_t)blk * XDBL_TILE))[t] = ((const float4*)sdbl)[t];
    }

    // ---- phase A scan: thread = (d, n-half) ----
    const int d = t >> 1, half = t & 1, n0 = half * 8;
    float4 A8a, A8b; float A0;
    bool structured = load_A8(A_logs, k, d, n0, A8a, A8b, A0);
    const float4* wp4 = (const float4*)(Wdt + (size_t)(k * DD + d) * RR);
    const float4 w0 = wp4[0], w1 = wp4[1];
    const float bz = bias[k * DD + d];
    const float Dval = Ds[k * DD + d];

    if (structured)
        scanA_body<true>(xs, sdbl, k, c, d, half, n0, A8a, A8b, w0, w1, bz,
                         Dval, S_g, dtsum);
    else
        scanA_body<false>(xs, sdbl, k, c, d, half, n0, A8a, A8b, w0, w1, bz,
                          Dval, S_g, dtsum);

    // ---- transposed y store (intra-wave pair data; no barrier needed) ----
    {
        float* base = oy + ((size_t)(k * DD + d)) * LL + l0 + half * 8;
        #pragma unroll
        for (int p = 0; p < 2; p++) {
            int j = p * 4;
            float4 v = make_float4(xs[(half * 8 + j + 0) * XST + d],
                                   xs[(half * 8 + j + 1) * XST + d],
                                   xs[(half * 8 + j + 2) * XST + d],
                                   xs[(half * 8 + j + 3) * XST + d]);
            *(float4*)(base + j) = v;
        }
    }
}

// ---------------------------------------------------------------------------
// K2: sequential combine across 256 chunks; S <- true h0, in place.
// ---------------------------------------------------------------------------
__global__ __launch_bounds__(256) void k2_combine(
    float* __restrict__ S_g, const float* __restrict__ dtsum,
    const float* __restrict__ A_logs)
{
    int tid = blockIdx.x * 256 + threadIdx.x;   // k*2048 + d*16 + n
    int kk = tid >> 11, rem = tid & 2047, dd2 = rem >> 4;
    float Ac = -__expf(A_logs[tid]);
    float hh = 0.0f;
    #pragma unroll 8
    for (int c2 = 0; c2 < NC; c2++) {
        size_t base = ((size_t)(kk * NC + c2)) * 2048 + rem;
        float s = S_g[base];
        float dsv = dtsum[(kk * NC + c2) * DD + dd2];
        S_g[base] = hh;
        hh = s + __expf(dsv * Ac) * hh;
    }
}

// ---------------------------------------------------------------------------
// K3 body: y(l) += C(l) . (exp(Dsum_l * A) (.) h0). All-scalar state.
// Structured: running product Q + 7-FMA Horner in named components.
// ---------------------------------------------------------------------------
template<bool S>
__device__ __forceinline__ void corr_body(
    float* ybuf, const float* sdbl, int d, int half, int n0,
    float4 A8a, float4 A8b, float4 h0A, float4 h0B,
    float4 w0, float4 w1, float bz)
{
    if constexpr (S) {
        float Q = 1.0f;
        #pragma unroll 1
        for (int i2 = 0; i2 < LC; i2 += 2) {
            float z = delta_row_z(sdbl, i2 + half, w0, w1, bz);
            float E = __expf(-fabsf(z));
            float q = (z >= 0.0f ? E : 1.0f) * __builtin_amdgcn_rcpf(1.0f + E);
            float qo = __shfl_xor(q, 1);
            float q0 = half ? qo : q, q1 = half ? q : qo;
            #pragma unroll
            for (int s = 0; s < 2; s++) {
                int i = i2 + s;
                Q *= (s ? q1 : q0);
                const float4* cp = (const float4*)(&sdbl[i * SDST + 24 + n0]);
                float4 c0 = cp[0], c1 = cp[1];
                float sH =          h0B.w * c1.w;
                sH = sH * Q + h0B.z * c1.z;
                sH = sH * Q + h0B.y * c1.y;
                sH = sH * Q + h0B.x * c1.x;
                sH = sH * Q + h0A.w * c0.w;
                sH = sH * Q + h0A.z * c0.z;
                sH = sH * Q + h0A.y * c0.y;
                sH = sH * Q + h0A.x * c0.x;
                float Q2 = Q * Q, Q4 = Q2 * Q2, Q8 = Q4 * Q4;
                float Qp = half ? Q8 * Q : Q;
                float yp = sH * Qp;
                float yv = yp + __shfl_xor(yp, 1);
                if (!half) ybuf[i * XST + d] = yv;
            }
        }
    } else {
        float Dsum = 0.0f;
        #pragma unroll 1
        for (int i2 = 0; i2 < LC; i2 += 2) {
            float z = delta_row_z(sdbl, i2 + half, w0, w1, bz);
            float E = __expf(-fabsf(z));
            float dt = fmaxf(z, 0.0f) + __logf(1.0f + E);
            float dto = __shfl_xor(dt, 1);
            float dt0 = half ? dto : dt, dt1 = half ? dt : dto;
            #pragma unroll
            for (int s = 0; s < 2; s++) {
                int i = i2 + s;
                Dsum += (s ? dt1 : dt0);
                const float4* cp = (const float4*)(&sdbl[i * SDST + 24 + n0]);
                float4 c0 = cp[0], c1 = cp[1];
                float yp = __expf(Dsum * A8a.x) * h0A.x * c0.x
                         + __expf(Dsum * A8a.y) * h0A.y * c0.y
                         + __expf(Dsum * A8a.z) * h0A.z * c0.z
                         + __expf(Dsum * A8a.w) * h0A.w * c0.w
                         + __expf(Dsum * A8b.x) * h0B.x * c1.x
                         + __expf(Dsum * A8b.y) * h0B.y * c1.y
                         + __expf(Dsum * A8b.z) * h0B.z * c1.z
                         + __expf(Dsum * A8b.w) * h0B.w * c1.w;
                float yv = yp + __shfl_xor(yp, 1);
                if (!half) ybuf[i * XST + d] = yv;
            }
        }
    }
}

__global__ __launch_bounds__(256, 4) void k3_corr(
    const float* __restrict__ Wdt, const float* __restrict__ bias,
    const float* __restrict__ A_logs, const float* __restrict__ S_g,
    const float* __restrict__ xdbl, float* __restrict__ oy)
{
    const int blk = blockIdx.x;
    const int k = blk >> 8;
    const int c = blk & 255;
    if (c == 0) return;                 // chunk 0 has h0 = 0
    const int l0 = c * LC;
    const int t = threadIdx.x;

    __shared__ __align__(16) float sdbl[LC * SDST];
    __shared__ __align__(16) float ybuf[LC * XST];
    if (t < XDBL_TILE / 4) {
        ((float4*)sdbl)[t] = ((const float4*)(xdbl + (size_t)blk * XDBL_TILE))[t];
    }
    __syncthreads();

    const int d = t >> 1, half = t & 1, n0 = half * 8;
    float4 A8a, A8b; float A0;
    bool structured = load_A8(A_logs, k, d, n0, A8a, A8b, A0);
    const float4* wp4 = (const float4*)(Wdt + (size_t)(k * DD + d) * RR);
    const float4 w0 = wp4[0], w1 = wp4[1];
    const float bz = bias[k * DD + d];

    const float4* hp = (const float4*)(S_g + (((size_t)(k * NC + c) * DD + d) * NN + n0));
    float4 h0A = hp[0], h0B = hp[1];

    if (structured)
        corr_body<true>(ybuf, sdbl, d, half, n0, A8a, A8b, h0A, h0B, w0, w1, bz);
    else
        corr_body<false>(ybuf, sdbl, d, half, n0, A8a, A8b, h0A, h0B, w0, w1, bz);

    // ---- transposed RMW of oy tile (intra-wave pair data) ----
    {
        float* base = oy + ((size_t)(k * DD + d)) * LL + l0 + half * 8;
        #pragma unroll
        for (int p = 0; p < 2; p++) {
            int j = p * 4;
            float4 v = *(float4*)(base + j);
            v.x += ybuf[(half * 8 + j + 0) * XST + d];
            v.y += ybuf[(half * 8 + j + 1) * XST + d];
            v.z += ybuf[(half * 8 + j + 2) * XST + d];
            v.w += ybuf[(half * 8 + j + 3) * XST + d];
            *(float4*)(base + j) = v;
        }
    }
}

// ---------------------------------------------------------------------------
// K4: restore + merge (reference's (D,L)-flat reshape semantics), float4.
// ---------------------------------------------------------------------------
__global__ __launch_bounds__(256) void k4_merge(
    const float* __restrict__ out_y, const float* __restrict__ mw,
    const float* __restrict__ mb, float* __restrict__ out)
{
    int idx4 = blockIdx.x * 256 + threadIdx.x;   // float4 index
    int dd4 = (idx4 & 31) * 4;
    int p = idx4 >> 5;
    int i3 = p & 15, i2 = (p >> 4) & 15, i1 = (p >> 8) & 15;

    float b = mb[0];
    float4 accv = make_float4(b, b, b, b);
    #pragma unroll
    for (int k = 0; k < 12; k++) {
        int a1 = i1, a2 = i2, a3 = i3;
        if (k & 1) { a1 = 15 - i1; a2 = 15 - i2; a3 = 15 - i3; }
        int j1, j2, j3;
        switch (k >> 1) {
            case 0:  j1 = a1; j2 = a2; j3 = a3; break;
            case 1:  j1 = a1; j2 = a3; j3 = a2; break;
            case 2:  j1 = a3; j2 = a2; j3 = a1; break;
            case 3:  j1 = a3; j2 = a1; j3 = a2; break;
            case 4:  j1 = a2; j2 = a1; j3 = a3; break;
            default: j1 = a2; j2 = a3; j3 = a1; break;
        }
        int jb = (j1 << 8) | (j2 << 4) | j3;
        float4 v = *(const float4*)(out_y + (size_t)k * (DD * LL) + (jb >> 5) * LL
                                    + ((jb & 31) << 7) + dd4);
        float w = mw[k];
        accv.x += w * v.x; accv.y += w * v.y;
        accv.z += w * v.z; accv.w += w * v.w;
    }
    *(float4*)(out + (size_t)p * DD + dd4) = accv;
}

extern "C" void kernel_launch(void* const* d_in, const int* in_sizes, int n_in,
                              void* d_out, int out_size, void* d_ws, size_t ws_size,
                              hipStream_t stream) {
    const float* x      = (const float*)d_in[0];
    const float* Wp     = (const float*)d_in[1];
    const float* Wdt    = (const float*)d_in[2];
    const float* bias   = (const float*)d_in[3];
    const float* A_logs = (const float*)d_in[4];
    const float* Ds     = (const float*)d_in[5];
    const float* mw     = (const float*)d_in[6];
    const float* mb     = (const float*)d_in[7];
    float* out = (float*)d_out;

    float* ws   = (float*)d_ws;
    float* S_g  = ws;                                 // K*NC*D*N = 6291456
    float* dts  = S_g + (size_t)KK * NC * DD * NN;    // K*NC*D   =  393216
    float* oy   = dts + (size_t)KK * NC * DD;         // K*D*L    = 6291456
    float* xdbl = oy + (size_t)KK * DD * LL;          // 3072*704 = 2162688

    k1_proj_scanA<<<dim3(KK * NC), dim3(256), 0, stream>>>(
        x, Wp, Wdt, bias, A_logs, Ds, S_g, dts, oy, xdbl);
    k2_combine<<<dim3(KK * DD * NN / 256), dim3(256), 0, stream>>>(S_g, dts, A_logs);
    k3_corr<<<dim3(KK * NC), dim3(256), 0, stream>>>(Wdt, bias, A_logs, S_g, xdbl, oy);
    k4_merge<<<dim3(LL * DD / 1024), dim3(256), 0, stream>>>(oy, mw, mb, out);
}

// Round 14
// 168.697 us; speedup vs baseline: 3.6790x; 3.6790x over previous
//
#include <hip/hip_runtime.h>

#define KK 12
#define LL 4096
#define DD 128
#define NN 16
#define RR 8
#define NC 128             // chunks (one per block) — R8-proven config
#define LC 32              // chunk length
#define XST 132            // x-tile / ybuf LDS stride (floats)
#define SDST 44            // x_dbl LDS row stride (floats)
#define XDBL_TILE (LC * SDST)   // 1408 floats per (k,chunk) tile

__device__ __forceinline__ int pos_of(int k, int l) {
    int o = k >> 1;
    int le = (k & 1) ? (4095 - l) : l;
    int t1 = le >> 8, t2 = (le >> 4) & 15, t3 = le & 15;
    switch (o) {
        case 0:  return (t1 << 8) | (t2 << 4) | t3;
        case 1:  return (t1 << 8) | (t3 << 4) | t2;
        case 2:  return (t3 << 8) | (t2 << 4) | t1;
        case 3:  return (t2 << 8) | (t3 << 4) | t1;
        case 4:  return (t2 << 8) | (t1 << 4) | t3;
        default: return (t3 << 8) | (t1 << 4) | t2;
    }
}

__device__ __forceinline__ float delta_row_z(const float* sdbl, int l,
                                             float4 w0, float4 w1, float bz) {
    const float4* dr = (const float4*)(sdbl + l * SDST);
    float4 r0 = dr[0], r1 = dr[1];
    return bz + w0.x * r0.x + w0.y * r0.y + w0.z * r0.z + w0.w * r0.w
              + w1.x * r1.x + w1.y * r1.y + w1.z * r1.z + w1.w * r1.w;
}

// Each thread owns 4 n-values (n0 = q*4). Structured requires A[n]=(n+1)*A0
// and A0 == -1 so exp(dt*A0) == exp(-dt) == (z>=0?E:1)/(1+E).
__device__ __forceinline__ bool load_A4(const float* __restrict__ A_logs,
                                        int k, int d, int n0,
                                        float4& A4, float& A0) {
    A4 = *(const float4*)(A_logs + ((size_t)(k * DD + d) * NN + n0));
    A4.x = -__expf(A4.x); A4.y = -__expf(A4.y);
    A4.z = -__expf(A4.z); A4.w = -__expf(A4.w);
    A0 = -__expf(A_logs[(size_t)(k * DD + d) * NN]);
    float aA0 = fabsf(A0);
    bool s = (fabsf(A0 + 1.0f) <= 1e-5f);
    s = s && (fabsf(A4.x - (float)(n0 + 1) * A0) <= 1e-4f * (float)(n0 + 1) * aA0);
    s = s && (fabsf(A4.y - (float)(n0 + 2) * A0) <= 1e-4f * (float)(n0 + 2) * aA0);
    s = s && (fabsf(A4.z - (float)(n0 + 3) * A0) <= 1e-4f * (float)(n0 + 3) * aA0);
    s = s && (fabsf(A4.w - (float)(n0 + 4) * A0) <= 1e-4f * (float)(n0 + 4) * aA0);
    return s;
}

// 4-lane-group uniform AND of a predicate (avoids divergent-branch shuffles).
__device__ __forceinline__ bool group_and4(bool v) {
    int si = v ? 1 : 0;
    si &= __shfl_xor(si, 1);
    si &= __shfl_xor(si, 2);
    return si != 0;
}

// ---------------------------------------------------------------------------
// One scan step. Thread = (d, q); 4 n-values in one float4 h.
// ---------------------------------------------------------------------------
template<bool S>
__device__ __forceinline__ void scan_step(
    float* xs, const float* sdbl, int i, int d, int q, int n0,
    float4 A4, float dt, float qp, float Dval,
    float4& h, float& dsum)
{
    float u = xs[i * XST + d];
    dsum += dt;
    float tu = dt * u;
    float4 e;
    if constexpr (S) {
        float qp2 = qp * qp, qp4 = qp2 * qp2, qp8 = qp4 * qp4;
        float p = qp * ((q & 1) ? qp4 : 1.0f) * ((q & 2) ? qp8 : 1.0f); // qp^(n0+1)
        e.x = p; e.y = p * qp; e.z = e.y * qp; e.w = e.z * qp;
    } else {
        e.x = __expf(dt * A4.x); e.y = __expf(dt * A4.y);
        e.z = __expf(dt * A4.z); e.w = __expf(dt * A4.w);
    }
    float4 b  = *(const float4*)(&sdbl[i * SDST + 8 + n0]);
    float4 cc = *(const float4*)(&sdbl[i * SDST + 24 + n0]);
    h.x = e.x * h.x + tu * b.x;  h.y = e.y * h.y + tu * b.y;
    h.z = e.z * h.z + tu * b.z;  h.w = e.w * h.w + tu * b.w;
    float d0 = h.x * cc.x + h.y * cc.y;
    float d1 = h.z * cc.z + h.w * cc.w;
    float yp = d0 + d1;
    float s1 = yp + __shfl_xor(yp, 1);
    float s2 = s1 + __shfl_xor(s1, 2);
    if (q == 0) xs[i * XST + d] = s2 + Dval * u;
}

// ---------------------------------------------------------------------------
// K1 scan body. 4-lane delta: lane q computes softplus for row i4+q, then
// broadcasts via width-4 shfl. 8 outer iterations at LC=32.
// ---------------------------------------------------------------------------
template<bool S>
__device__ __forceinline__ void scanA_body(
    float* xs, const float* sdbl, int k, int c,
    int d, int q, int n0, float4 A4,
    float4 w0, float4 w1, float bz, float Dval,
    float* __restrict__ S_g, float* __restrict__ dtsum)
{
    float4 h = make_float4(0.f, 0.f, 0.f, 0.f);
    float dsum = 0.0f;

    #pragma unroll 1
    for (int i4 = 0; i4 < LC; i4 += 4) {
        float z = delta_row_z(sdbl, i4 + q, w0, w1, bz);
        float E = __expf(-fabsf(z));
        float opE = 1.0f + E;
        float dt_me = fmaxf(z, 0.0f) + __logf(opE);
        float qp_me = 0.0f;
        if constexpr (S)
            qp_me = (z >= 0.0f ? E : 1.0f) * __builtin_amdgcn_rcpf(opE);
        #pragma unroll
        for (int s = 0; s < 4; s++) {
            float dt = __shfl(dt_me, s, 4);
            float qp = S ? __shfl(qp_me, s, 4) : 0.0f;
            scan_step<S>(xs, sdbl, i4 + s, d, q, n0, A4, dt, qp, Dval, h, dsum);
        }
    }

    *(float4*)(S_g + (((size_t)(k * NC + c) * DD + d) * NN + n0)) = h;
    if (q == 0) dtsum[(k * NC + c) * DD + d] = dsum;
}

// ---------------------------------------------------------------------------
// K1: proj GEMM + phase A local scan. Block = (k, 32-l chunk), 512 threads:
// thread = (d, q) 4-way n-split -> 12288 total waves (2x R8) for latency
// hiding. GEMM phase is R8-byte-exact, gated to t<256. LDS 23 KB.
// ---------------------------------------------------------------------------
__global__ __launch_bounds__(512, 8) void k1_proj_scanA(
    const float* __restrict__ x, const float* __restrict__ Wp,
    const float* __restrict__ Wdt, const float* __restrict__ bias,
    const float* __restrict__ A_logs, const float* __restrict__ Ds,
    float* __restrict__ S_g, float* __restrict__ dtsum,
    float* __restrict__ oy, float* __restrict__ xdbl)
{
    const int blk = blockIdx.x;
    const int k = blk >> 7;
    const int c = blk & 127;
    const int l0 = c * LC;
    const int t = threadIdx.x;

    __shared__ __align__(16) float xs[LC * XST];    // x-tile [l][d]; y overwrites
    __shared__ __align__(16) float sdbl[LC * SDST]; // x_dbl [l][ch]
    __shared__ int pos_s[LC];

    if (t < LC) pos_s[t] = pos_of(k, l0 + t);
    __syncthreads();

    // ---- stage x tile: 2 passes x 16 rows x 32 lanes b128 (coalesced) ----
    {
        int lane32 = t & 31, rowi = t >> 5;   // rowi 0..15
        #pragma unroll
        for (int p = 0; p < 2; p++) {
            int l = p * 16 + rowi;
            float4 v = *(const float4*)(x + (size_t)pos_s[l] * DD + lane32 * 4);
            *(float4*)(&xs[l * XST + lane32 * 4]) = v;
        }
    }
    __syncthreads();

    // ---- projection GEMM (R8-exact, first 256 threads) ----
    if (t < 256) {
        int l = t & 31, cg = t >> 5;          // cg 0..7, 5 channels each
        float acc[5];
        #pragma unroll
        for (int j = 0; j < 5; j++) acc[j] = 0.0f;
        const float* wk = Wp + (size_t)(k * 40 + cg * 5) * DD;
        for (int d4 = 0; d4 < DD; d4 += 4) {
            float4 xv = *(const float4*)(&xs[l * XST + d4]);
            #pragma unroll
            for (int j = 0; j < 5; j++) {
                const float* w = wk + j * DD + d4;
                acc[j] += xv.x * w[0] + xv.y * w[1] + xv.z * w[2] + xv.w * w[3];
            }
        }
        #pragma unroll
        for (int j = 0; j < 5; j++) sdbl[l * SDST + cg * 5 + j] = acc[j];
    }
    __syncthreads();

    // ---- spill x_dbl tile for K3 (352 float4s, single shot) ----
    if (t < XDBL_TILE / 4) {
        ((float4*)(xdbl + (size_t)blk * XDBL_TILE))[t] = ((const float4*)sdbl)[t];
    }

    // ---- phase A scan: thread = (d, quarter) ----
    const int d = t >> 2, q = t & 3, n0 = q * 4;
    float4 A4; float A0;
    bool structured = group_and4(load_A4(A_logs, k, d, n0, A4, A0));
    const float4* wp4 = (const float4*)(Wdt + (size_t)(k * DD + d) * RR);
    const float4 w0 = wp4[0], w1 = wp4[1];
    const float bz = bias[k * DD + d];
    const float Dval = Ds[k * DD + d];

    if (structured)
        scanA_body<true>(xs, sdbl, k, c, d, q, n0, A4, w0, w1, bz,
                         Dval, S_g, dtsum);
    else
        scanA_body<false>(xs, sdbl, k, c, d, q, n0, A4, w0, w1, bz,
                          Dval, S_g, dtsum);

    // ---- transposed y store: lane q covers rows q*8..q*8+7 of column d ----
    {
        float* base = oy + ((size_t)(k * DD + d)) * LL + l0 + q * 8;
        #pragma unroll
        for (int p = 0; p < 2; p++) {
            int j = p * 4;
            float4 v = make_float4(xs[(q * 8 + j + 0) * XST + d],
                                   xs[(q * 8 + j + 1) * XST + d],
                                   xs[(q * 8 + j + 2) * XST + d],
                                   xs[(q * 8 + j + 3) * XST + d]);
            *(float4*)(base + j) = v;
        }
    }
}

// ---------------------------------------------------------------------------
// K2: sequential combine across 128 chunks; S <- true h0, in place. (R8-exact)
// ---------------------------------------------------------------------------
__global__ __launch_bounds__(256) void k2_combine(
    float* __restrict__ S_g, const float* __restrict__ dtsum,
    const float* __restrict__ A_logs)
{
    int tid = blockIdx.x * 256 + threadIdx.x;   // k*2048 + d*16 + n
    int kk = tid >> 11, rem = tid & 2047, dd2 = rem >> 4;
    float Ac = -__expf(A_logs[tid]);
    float hh = 0.0f;
    #pragma unroll 8
    for (int c2 = 0; c2 < NC; c2++) {
        size_t base = ((size_t)(kk * NC + c2)) * 2048 + rem;
        float s = S_g[base];
        float dsv = dtsum[(kk * NC + c2) * DD + dd2];
        S_g[base] = hh;
        hh = s + __expf(dsv * Ac) * hh;
    }
}

// ---------------------------------------------------------------------------
// K3 body: y(l) += C(l) . (exp(Dsum_l * A) (.) h0). Thread = (d, q).
// Structured: running product Q; per-thread 3-FMA Horner + Q^(n0+1) factor.
// ---------------------------------------------------------------------------
template<bool S>
__device__ __forceinline__ void corr_body(
    float* ybuf, const float* sdbl, int d, int q, int n0,
    float4 A4, float4 h0, float4 w0, float4 w1, float bz)
{
    if constexpr (S) {
        float Q = 1.0f;
        #pragma unroll 1
        for (int i4 = 0; i4 < LC; i4 += 4) {
            float z = delta_row_z(sdbl, i4 + q, w0, w1, bz);
            float E = __expf(-fabsf(z));
            float qp_me = (z >= 0.0f ? E : 1.0f) * __builtin_amdgcn_rcpf(1.0f + E);
            #pragma unroll
            for (int s = 0; s < 4; s++) {
                int i = i4 + s;
                Q *= __shfl(qp_me, s, 4);
                float4 cc = *(const float4*)(&sdbl[i * SDST + 24 + n0]);
                float sH =          h0.w * cc.w;
                sH = sH * Q + h0.z * cc.z;
                sH = sH * Q + h0.y * cc.y;
                sH = sH * Q + h0.x * cc.x;
                float Q2 = Q * Q, Q4 = Q2 * Q2, Q8 = Q4 * Q4;
                float Qp = Q * ((q & 1) ? Q4 : 1.0f) * ((q & 2) ? Q8 : 1.0f);
                float yp = sH * Qp;
                float s1 = yp + __shfl_xor(yp, 1);
                float s2 = s1 + __shfl_xor(s1, 2);
                if (q == 0) ybuf[i * XST + d] = s2;
            }
        }
    } else {
        float Dsum = 0.0f;
        #pragma unroll 1
        for (int i4 = 0; i4 < LC; i4 += 4) {
            float z = delta_row_z(sdbl, i4 + q, w0, w1, bz);
            float E = __expf(-fabsf(z));
            float dt_me = fmaxf(z, 0.0f) + __logf(1.0f + E);
            #pragma unroll
            for (int s = 0; s < 4; s++) {
                int i = i4 + s;
                Dsum += __shfl(dt_me, s, 4);
                float4 cc = *(const float4*)(&sdbl[i * SDST + 24 + n0]);
                float yp = __expf(Dsum * A4.x) * h0.x * cc.x
                         + __expf(Dsum * A4.y) * h0.y * cc.y
                         + __expf(Dsum * A4.z) * h0.z * cc.z
                         + __expf(Dsum * A4.w) * h0.w * cc.w;
                float s1 = yp + __shfl_xor(yp, 1);
                float s2 = s1 + __shfl_xor(s1, 2);
                if (q == 0) ybuf[i * XST + d] = s2;
            }
        }
    }
}

__global__ __launch_bounds__(512, 8) void k3_corr(
    const float* __restrict__ Wdt, const float* __restrict__ bias,
    const float* __restrict__ A_logs, const float* __restrict__ S_g,
    const float* __restrict__ xdbl, float* __restrict__ oy)
{
    const int blk = blockIdx.x;
    const int k = blk >> 7;
    const int c = blk & 127;
    if (c == 0) return;                 // chunk 0 has h0 = 0
    const int l0 = c * LC;
    const int t = threadIdx.x;

    __shared__ __align__(16) float sdbl[LC * SDST];
    __shared__ __align__(16) float ybuf[LC * XST];
    if (t < XDBL_TILE / 4) {
        ((float4*)sdbl)[t] = ((const float4*)(xdbl + (size_t)blk * XDBL_TILE))[t];
    }
    __syncthreads();

    const int d = t >> 2, q = t & 3, n0 = q * 4;
    float4 A4; float A0;
    bool structured = group_and4(load_A4(A_logs, k, d, n0, A4, A0));
    const float4* wp4 = (const float4*)(Wdt + (size_t)(k * DD + d) * RR);
    const float4 w0 = wp4[0], w1 = wp4[1];
    const float bz = bias[k * DD + d];

    float4 h0 = *(const float4*)(S_g + (((size_t)(k * NC + c) * DD + d) * NN + n0));

    if (structured)
        corr_body<true>(ybuf, sdbl, d, q, n0, A4, h0, w0, w1, bz);
    else
        corr_body<false>(ybuf, sdbl, d, q, n0, A4, h0, w0, w1, bz);

    // ---- transposed RMW of oy tile: lane q covers rows q*8..q*8+7 ----
    {
        float* base = oy + ((size_t)(k * DD + d)) * LL + l0 + q * 8;
        #pragma unroll
        for (int p = 0; p < 2; p++) {
            int j = p * 4;
            float4 v = *(float4*)(base + j);
            v.x += ybuf[(q * 8 + j + 0) * XST + d];
            v.y += ybuf[(q * 8 + j + 1) * XST + d];
            v.z += ybuf[(q * 8 + j + 2) * XST + d];
            v.w += ybuf[(q * 8 + j + 3) * XST + d];
            *(float4*)(base + j) = v;
        }
    }
}

// ---------------------------------------------------------------------------
// K4: restore + merge (reference's (D,L)-flat reshape semantics), float4.
// ---------------------------------------------------------------------------
__global__ __launch_bounds__(256) void k4_merge(
    const float* __restrict__ out_y, const float* __restrict__ mw,
    const float* __restrict__ mb, float* __restrict__ out)
{
    int idx4 = blockIdx.x * 256 + threadIdx.x;   // float4 index
    int dd4 = (idx4 & 31) * 4;
    int p = idx4 >> 5;
    int i3 = p & 15, i2 = (p >> 4) & 15, i1 = (p >> 8) & 15;

    float b = mb[0];
    float4 accv = make_float4(b, b, b, b);
    #pragma unroll
    for (int k = 0; k < 12; k++) {
        int a1 = i1, a2 = i2, a3 = i3;
        if (k & 1) { a1 = 15 - i1; a2 = 15 - i2; a3 = 15 - i3; }
        int j1, j2, j3;
        switch (k >> 1) {
            case 0:  j1 = a1; j2 = a2; j3 = a3; break;
            case 1:  j1 = a1; j2 = a3; j3 = a2; break;
            case 2:  j1 = a3; j2 = a2; j3 = a1; break;
            case 3:  j1 = a3; j2 = a1; j3 = a2; break;
            case 4:  j1 = a2; j2 = a1; j3 = a3; break;
            default: j1 = a2; j2 = a3; j3 = a1; break;
        }
        int jb = (j1 << 8) | (j2 << 4) | j3;
        float4 v = *(const float4*)(out_y + (size_t)k * (DD * LL) + (jb >> 5) * LL
                                    + ((jb & 31) << 7) + dd4);
        float w = mw[k];
        accv.x += w * v.x; accv.y += w * v.y;
        accv.z += w * v.z; accv.w += w * v.w;
    }
    *(float4*)(out + (size_t)p * DD + dd4) = accv;
}

extern "C" void kernel_launch(void* const* d_in, const int* in_sizes, int n_in,
                              void* d_out, int out_size, void* d_ws, size_t ws_size,
                              hipStream_t stream) {
    const float* x      = (const float*)d_in[0];
    const float* Wp     = (const float*)d_in[1];
    const float* Wdt    = (const float*)d_in[2];
    const float* bias   = (const float*)d_in[3];
    const float* A_logs = (const float*)d_in[4];
    const float* Ds     = (const float*)d_in[5];
    const float* mw     = (const float*)d_in[6];
    const float* mb     = (const float*)d_in[7];
    float* out = (float*)d_out;

    float* ws   = (float*)d_ws;
    float* S_g  = ws;                                 // K*NC*D*N = 1572864
    float* dts  = S_g + (size_t)KK * NC * DD * NN;    // K*NC*D   =   98304
    float* oy   = dts + (size_t)KK * NC * DD;         // K*D*L    = 6291456
    float* xdbl = oy + (size_t)KK * DD * LL;          // 1536*1408 = 2162688

    k1_proj_scanA<<<dim3(KK * NC), dim3(512), 0, stream>>>(
        x, Wp, Wdt, bias, A_logs, Ds, S_g, dts, oy, xdbl);
    k2_combine<<<dim3(KK * DD * NN / 256), dim3(256), 0, stream>>>(S_g, dts, A_logs);
    k3_corr<<<dim3(KK * NC), dim3(512), 0, stream>>>(Wdt, bias, A_logs, S_g, xdbl, oy);
    k4_merge<<<dim3(LL * DD / 1024), dim3(256), 0, stream>>>(oy, mw, mb, out);
}